// Round 18
// baseline (173.537 us; speedup 1.0000x reference)
//
#include <hip/hip_runtime.h>
#include <cstddef>

#define T_STEPS 256
#define OBS     32
#define ACTD    8
#define NB      16      // sequences per block (full N-dim of transposed MFMA)
#define HPAD2   152     // Bop row stride in f16 (304 B)
#define NSEQ    4096

typedef _Float16 f16x8 __attribute__((ext_vector_type(8)));
typedef _Float16 f16x4 __attribute__((ext_vector_type(4)));
typedef _Float16 f16x2 __attribute__((ext_vector_type(2)));
typedef float    f32x4 __attribute__((ext_vector_type(4)));

union F8 { f16x8 v; _Float16 e[8]; f16x2 h2[4]; };
union F4 { f16x4 v; _Float16 e[4]; f16x2 h2[2]; };

#define LOG2E 1.44269504088896f

__device__ __forceinline__ f16x2 pkrtz(float a, float b) {
    return __builtin_bit_cast(f16x2, __builtin_amdgcn_cvt_pkrtz(a, b));
}

// one LSTM unit update from gates {i,j,f,o}; cr is the (negated-c) running state.
// Identical formulas/order to R17 (bit-compatible).
__device__ __forceinline__ float cell_update(float gi, float gj, float gf, float go,
                                             float& cr) {
    float ef = __builtin_amdgcn_exp2f(gf * -LOG2E);
    float ei = __builtin_amdgcn_exp2f(gi * -LOG2E);
    float ej = __builtin_amdgcn_exp2f(gj * (-2.0f * LOG2E));
    float Fv = 1.0f + ef, Av = 1.0f + ei, Bv = 1.0f + ej;
    float AB = Av * Bv;
    float num = fmaf(cr, AB, Fv * (Bv - 2.0f));
    float c = num * __builtin_amdgcn_rcpf(Fv * AB);
    cr = c;
    float ec = __builtin_amdgcn_exp2f(c * (-2.0f * LOG2E));
    float eo = __builtin_amdgcn_exp2f(go * -LOG2E);
    float Dv = 1.0f + ec, Ev = 1.0f + eo;
    return (Dv - 2.0f) * __builtin_amdgcn_rcpf(Dv * Ev);
}

__global__ __launch_bounds__(512)
void lstm_fused(const float* __restrict__ obss, const float* __restrict__ actions,
                const float* __restrict__ W, const float* __restrict__ b,
                const float* __restrict__ Wdec, const float* __restrict__ bdec_p,
                float* __restrict__ out)
{
    // Two-barrier pipeline per step:
    //  alpha: h_t-1 visible. A: 8 h-MFMAs (into precomputed x-partials), hand units
    //         r=2,3 gates to accbuf. B: cvt+stage x_{t+1}, output duty.
    //  beta:  accbuf visible. A: update units 0,1 + h-write + x-partials for t+1.
    //         B: update units 2,3 + h-write. Both write decode partials.
    __shared__ __align__(16) _Float16 Bop[2][NB * HPAD2];
    __shared__ __align__(16) float partb[2][16][36];       // slots 0-15 A, 16-31 B
    __shared__ __align__(16) float accbuf[4][4][16][12];   // [w][g][m][8 used of 12]

    const int tid  = threadIdx.x;
    const int w8   = tid >> 6;            // physical wave 0..7
    const int w    = w8 & 3;              // unit-slice 0..3
    const bool isA = w8 < 4;
    const int lane = tid & 63;
    const int g    = lane >> 4;
    const int m    = lane & 15;           // seq
    const int n0   = blockIdx.x * NB;
    const int u0   = 16 * w + 4 * g;
    const int sigb = 32 * (w >> 1) + 8 * g + 4 * (w & 1);  // = phi(u0)

    // ---- A-waves: all W fragments (4 gates x 4 K-tiles) ----
    f16x8 AW[4][4];
    if (isA) {
        const float* Wc = W + 16 * w + m;
#pragma unroll
        for (int e = 0; e < 4; e++) {
#pragma unroll
            for (int c = 0; c < 2; c++) {
                F8 hi;
#pragma unroll
                for (int i = 0; i < 8; i++) {
                    int k = 32 * c + 16 * (i >> 2) + 4 * g + (i & 3);
                    hi.e[i] = (_Float16)Wc[(40 + k) * 256 + 64 * e];
                }
                AW[e][c] = hi.v;
            }
            F8 xo, xA;
            float bv = b[64 * e + 16 * w + m] + (e == 2 ? 1.0f : 0.0f);
#pragma unroll
            for (int i = 0; i < 8; i++) {
                int kk = 16 * (i >> 2) + 4 * g + (i & 3);
                xo.e[i] = (_Float16)Wc[kk * 256 + 64 * e];
                xA.e[i] = (kk < ACTD) ? (_Float16)Wc[(OBS + kk) * 256 + 64 * e]
                        : (kk == 16)  ? (_Float16)bv
                                      : (_Float16)0.0f;
            }
            AW[e][2] = xo.v;
            AW[e][3] = xA.v;
        }
    }
    f32x4 wdv = *(const f32x4*)&Wdec[u0];
    const float bd = bdec_p[0];

    for (int i = tid; i < 2 * NB * HPAD2; i += 512)
        (&Bop[0][0])[i] = (_Float16)0.0f;
    __syncthreads();
    if (tid < 32)
        Bop[tid >> 4][(tid & 15) * HPAD2 + 100] = (_Float16)1.0f;

    // ---- B-wave x pipeline ----
    const float* pO = obss    + ((size_t)(n0 + m) * T_STEPS) * OBS  + 4 * g;
    const float* pA = actions + ((size_t)(n0 + m) * T_STEPS) * ACTD + 4 * g;
    f32x4 xo0 = {0,0,0,0}, xo1 = {0,0,0,0}, xa = {0,0,0,0};
    auto loadx = [&]() {
        xo0 = *(const f32x4*)pO;
        xo1 = *(const f32x4*)(pO + 16);
        pO += OBS;
        if (g < 2) { xa = *(const f32x4*)pA; pA += ACTD; }
    };
    f16x8 bxo;
    f16x4 uaq;
    auto cvtx = [&]() {
        F8 uo;
        uo.h2[0] = pkrtz(xo0[0], xo0[1]);
        uo.h2[1] = pkrtz(xo0[2], xo0[3]);
        uo.h2[2] = pkrtz(xo1[0], xo1[1]);
        uo.h2[3] = pkrtz(xo1[2], xo1[3]);
        F4 ua_;
        ua_.h2[0] = pkrtz(xa[0], xa[1]);
        ua_.h2[1] = pkrtz(xa[2], xa[3]);
        bxo = uo.v;
        uaq = ua_.v;
    };
    auto stagex = [&](int buf) {
        _Float16* xp = &Bop[buf][m * HPAD2 + 64];
        *(f16x8*)(xp + 8 * g) = bxo;
        if (g < 2) *(f16x4*)(xp + 32 + 8 * g) = uaq;
    };

    if (!isA) {
        loadx();          // x_0
        cvtx();
        stagex(0);
        loadx();          // x_1
    }
    float crA0 = 0.f, crA1 = 0.f;        // A: units u0+0, u0+1
    float crB2 = 0.f, crB3 = 0.f;        // B: units u0+2, u0+3
    float* pOut = out + (size_t)((w + 3) & 3) * NSEQ + n0 + lane;

    __syncthreads();

    // A: precompute x-partials for t=0 (Bop[0] staged by B above)
    f32x4 pP1[4], pP2[4];
    if (isA) {
        const _Float16* bq = &Bop[0][m * HPAD2];
        f16x8 f2 = *(const f16x8*)(bq + 64 + 8 * g);
        f16x8 f3 = *(const f16x8*)(bq + 96 + 8 * g);
        const f32x4 z = {0.f, 0.f, 0.f, 0.f};
#pragma unroll
        for (int e = 0; e < 4; e++) {
            pP1[e] = __builtin_amdgcn_mfma_f32_16x16x32_f16(AW[e][2], f2, z, 0, 0, 0);
            pP2[e] = __builtin_amdgcn_mfma_f32_16x16x32_f16(AW[e][3], f3, z, 0, 0, 0);
        }
    }

#pragma unroll 2
    for (int t = 0; t < T_STEPS; ++t) {
        const int cb  = t & 1;
        const int nb2 = cb ^ 1;
        asm volatile("s_waitcnt lgkmcnt(0)\n\ts_barrier" ::: "memory");   // alpha

        if (isA) {
            __builtin_amdgcn_s_setprio(1);
            const _Float16* bp = &Bop[cb][m * HPAD2];
            f16x8 f0 = *(const f16x8*)(bp + 8 * g);           // h k 0..31
            f16x8 f1 = *(const f16x8*)(bp + 32 + 8 * g);      // h k 32..63
            f32x4 acc[4];
#pragma unroll
            for (int e = 0; e < 4; e++) {
                f32x4 a1 = __builtin_amdgcn_mfma_f32_16x16x32_f16(AW[e][0], f0, pP1[e], 0, 0, 0);
                f32x4 a2 = __builtin_amdgcn_mfma_f32_16x16x32_f16(AW[e][1], f1, pP2[e], 0, 0, 0);
                acc[e] = a1 + a2;
            }
            // hand off units r=2,3 (exact f32)
            f32x4 t2 = {acc[0][2], acc[1][2], acc[2][2], acc[3][2]};
            f32x4 t3 = {acc[0][3], acc[1][3], acc[2][3], acc[3][3]};
            *(f32x4*)&accbuf[w][g][m][0] = t2;
            *(f32x4*)&accbuf[w][g][m][4] = t3;
            __builtin_amdgcn_s_setprio(0);
            asm volatile("s_waitcnt lgkmcnt(0)\n\ts_barrier" ::: "memory"); // beta

            // update units r=0,1
            float h0 = cell_update(acc[0][0], acc[1][0], acc[2][0], acc[3][0], crA0);
            float h1 = cell_update(acc[0][1], acc[1][1], acc[2][1], acc[3][1], crA1);
            *(f16x2*)(&Bop[nb2][m * HPAD2 + sigb]) = pkrtz(h0, h1);
            partb[cb][m][4 * w + g] = fmaf(h1, wdv[1], h0 * wdv[0]);

            // prefetch x_{t+1} frags + x-partials (staged by B pre-beta)
            if (t + 1 < T_STEPS) {
                const _Float16* bq = &Bop[nb2][m * HPAD2];
                f16x8 f2 = *(const f16x8*)(bq + 64 + 8 * g);
                f16x8 f3 = *(const f16x8*)(bq + 96 + 8 * g);
                const f32x4 z = {0.f, 0.f, 0.f, 0.f};
#pragma unroll
                for (int e = 0; e < 4; e++) {
                    pP1[e] = __builtin_amdgcn_mfma_f32_16x16x32_f16(AW[e][2], f2, z, 0, 0, 0);
                    pP2[e] = __builtin_amdgcn_mfma_f32_16x16x32_f16(AW[e][3], f3, z, 0, 0, 0);
                }
            }
        } else {
            // producer: stage x_{t+1}; issue x_{t+2}; output duty for row t-1
            if (t + 1 < T_STEPS) {
                cvtx();
                stagex(nb2);
            }
            if (t + 2 < T_STEPS) loadx();
            if (t > 0 && w == (t & 3) && lane < 16) {
                const float* pp = &partb[nb2][lane][0];
                f32x4 q0 = *(const f32x4*)pp;
                f32x4 q1 = *(const f32x4*)(pp + 4);
                f32x4 q2 = *(const f32x4*)(pp + 8);
                f32x4 q3 = *(const f32x4*)(pp + 12);
                f32x4 q4 = *(const f32x4*)(pp + 16);
                f32x4 q5 = *(const f32x4*)(pp + 20);
                f32x4 q6 = *(const f32x4*)(pp + 24);
                f32x4 q7 = *(const f32x4*)(pp + 28);
                f32x4 s4 = ((q0 + q1) + (q2 + q3)) + ((q4 + q5) + (q6 + q7));
                *pOut = s4[0] + s4[1] + s4[2] + s4[3] + bd;
                pOut += 4 * NSEQ;
            }
            asm volatile("s_waitcnt lgkmcnt(0)\n\ts_barrier" ::: "memory"); // beta

            // consume handoff: update units r=2,3
            f32x4 a2v = *(const f32x4*)&accbuf[w][g][m][0];
            f32x4 a3v = *(const f32x4*)&accbuf[w][g][m][4];
            float h2 = cell_update(a2v[0], a2v[1], a2v[2], a2v[3], crB2);
            float h3 = cell_update(a3v[0], a3v[1], a3v[2], a3v[3], crB3);
            *(f16x2*)(&Bop[nb2][m * HPAD2 + sigb + 2]) = pkrtz(h2, h3);
            partb[cb][m][16 + 4 * w + g] = fmaf(h3, wdv[3], h2 * wdv[2]);
        }
    }

    // final row (t = T_STEPS-1 partials in partb[1]); B-wave 0 serves it
    __syncthreads();
    if (!isA && w == 0 && lane < 16) {
        const float* pp = &partb[1][lane][0];
        f32x4 q0 = *(const f32x4*)pp;
        f32x4 q1 = *(const f32x4*)(pp + 4);
        f32x4 q2 = *(const f32x4*)(pp + 8);
        f32x4 q3 = *(const f32x4*)(pp + 12);
        f32x4 q4 = *(const f32x4*)(pp + 16);
        f32x4 q5 = *(const f32x4*)(pp + 20);
        f32x4 q6 = *(const f32x4*)(pp + 24);
        f32x4 q7 = *(const f32x4*)(pp + 28);
        f32x4 s4 = ((q0 + q1) + (q2 + q3)) + ((q4 + q5) + (q6 + q7));
        *pOut = s4[0] + s4[1] + s4[2] + s4[3] + bd;
    }
}

extern "C" void kernel_launch(void* const* d_in, const int* in_sizes, int n_in,
                              void* d_out, int out_size, void* d_ws, size_t ws_size,
                              hipStream_t stream) {
    (void)in_sizes; (void)n_in; (void)d_ws; (void)ws_size; (void)out_size;
    const float* obss    = (const float*)d_in[0];
    const float* actions = (const float*)d_in[1];
    const float* W       = (const float*)d_in[2];
    const float* b       = (const float*)d_in[3];
    const float* Wdec    = (const float*)d_in[4];
    const float* bdec    = (const float*)d_in[5];
    float* out = (float*)d_out;
    lstm_fused<<<dim3(NSEQ / NB), dim3(512), 0, stream>>>(obss, actions, W, b, Wdec, bdec, out);
}

// Round 19
// 148.196 us; speedup vs baseline: 1.1710x; 1.1710x over previous
//
#include <hip/hip_runtime.h>
#include <cstddef>

#define T_STEPS 256
#define OBS     32
#define ACTD    8
#define NB      16      // sequences per block (full N-dim of transposed MFMA)
#define HPADH   72      // Hbuf row stride in f16 (144 B; 36 dw == 4 mod 32, 2-way)
#define XPAD    72      // xb row stride in f16
#define NSEQ    4096

typedef _Float16 f16x8 __attribute__((ext_vector_type(8)));
typedef _Float16 f16x4 __attribute__((ext_vector_type(4)));
typedef _Float16 f16x2 __attribute__((ext_vector_type(2)));
typedef float    f32x4 __attribute__((ext_vector_type(4)));

union F8 { f16x8 v; _Float16 e[8]; f16x2 h2[4]; };
union F4 { f16x4 v; _Float16 e[4]; f16x2 h2[2]; };

#define LOG2E 1.44269504088896f

__device__ __forceinline__ f16x2 pkrtz(float a, float b) {
    return __builtin_bit_cast(f16x2, __builtin_amdgcn_cvt_pkrtz(a, b));
}

__global__ __launch_bounds__(512)
void lstm_fused(const float* __restrict__ obss, const float* __restrict__ actions,
                const float* __restrict__ W, const float* __restrict__ b,
                const float* __restrict__ Wdec, const float* __restrict__ bdec_p,
                float* __restrict__ out)
{
    // A-waves (0-3): depth-1 h-MFMAs (into x-partials precomputed at prev tail),
    //   cell update, h write, then tail x-MFMAs for t+1 from xb[(t+1)%3].
    // B-waves (4-7): x loads/cvt, stage x 2 steps ahead (xb triple buffer), duty.
    // Hbuf: row = seq, col = phi(unit). xb: row = seq, col = pi(x-dim)+bias slot 36.
    __shared__ __align__(16) _Float16 Hbuf[2][NB * HPADH];
    __shared__ __align__(16) _Float16 xb[3][NB * XPAD];
    __shared__ __align__(16) float partb[2][16][20];   // [buf][seq][16 partials]

    const int tid  = threadIdx.x;
    const int w8   = tid >> 6;            // physical wave 0..7
    const int w    = w8 & 3;              // unit-slice 0..3
    const bool isA = w8 < 4;
    const int lane = tid & 63;
    const int g    = lane >> 4;
    const int m    = lane & 15;           // seq
    const int n0   = blockIdx.x * NB;
    const int u0   = 16 * w + 4 * g;
    const int sigb = 32 * (w >> 1) + 8 * g + 4 * (w & 1);  // = phi(u0), 8B-aligned

    // ---- A-waves: all W fragments (4 gates x 4 K-tiles) ----
    f16x8 AW[4][4];
    f32x4 wdv = {0.f, 0.f, 0.f, 0.f};
    if (isA) {
        const float* Wc = W + 16 * w + m;     // tile e -> gate-col 64e + 16w + m
#pragma unroll
        for (int e = 0; e < 4; e++) {
#pragma unroll
            for (int c = 0; c < 2; c++) {     // h tiles: k 0..63 -> W row 40+k
                F8 hi;
#pragma unroll
                for (int i = 0; i < 8; i++) {
                    int k = 32 * c + 16 * (i >> 2) + 4 * g + (i & 3);
                    hi.e[i] = (_Float16)Wc[(40 + k) * 256 + 64 * e];
                }
                AW[e][c] = hi.v;
            }
            F8 xo, xA;
            float bv = b[64 * e + 16 * w + m] + (e == 2 ? 1.0f : 0.0f);
#pragma unroll
            for (int i = 0; i < 8; i++) {
                int kk = 16 * (i >> 2) + 4 * g + (i & 3);              // 0..31
                xo.e[i] = (_Float16)Wc[kk * 256 + 64 * e];             // obs dims
                xA.e[i] = (kk < ACTD) ? (_Float16)Wc[(OBS + kk) * 256 + 64 * e]
                        : (kk == 16)  ? (_Float16)bv                   // bias slot
                                      : (_Float16)0.0f;
            }
            AW[e][2] = xo.v;
            AW[e][3] = xA.v;
        }
        wdv = *(const f32x4*)&Wdec[u0];
    }
    const float bd = bdec_p[0];

    for (int i = tid; i < 2 * NB * HPADH; i += 512)
        (&Hbuf[0][0])[i] = (_Float16)0.0f;
    for (int i = tid; i < 3 * NB * XPAD; i += 512)
        (&xb[0][0])[i] = (_Float16)0.0f;
    __syncthreads();
    if (tid < 48)                          // bias B-val 1.0 at col 36, all 3 slots
        xb[tid >> 4][(tid & 15) * XPAD + 36] = (_Float16)1.0f;

    // ---- B-wave x pipeline (2-ahead staging) ----
    const float* pO = obss    + ((size_t)(n0 + m) * T_STEPS) * OBS  + 4 * g;
    const float* pA = actions + ((size_t)(n0 + m) * T_STEPS) * ACTD + 4 * g;
    f32x4 xo0 = {0,0,0,0}, xo1 = {0,0,0,0}, xa = {0,0,0,0};
    auto loadx = [&]() {
        xo0 = *(const f32x4*)pO;
        xo1 = *(const f32x4*)(pO + 16);
        pO += OBS;
        if (g < 2) { xa = *(const f32x4*)pA; pA += ACTD; }
    };
    f16x8 bxo;
    f16x4 uaq;
    auto cvtx = [&]() {
        F8 uo;
        uo.h2[0] = pkrtz(xo0[0], xo0[1]);
        uo.h2[1] = pkrtz(xo0[2], xo0[3]);
        uo.h2[2] = pkrtz(xo1[0], xo1[1]);
        uo.h2[3] = pkrtz(xo1[2], xo1[3]);
        F4 ua_;
        ua_.h2[0] = pkrtz(xa[0], xa[1]);
        ua_.h2[1] = pkrtz(xa[2], xa[3]);
        bxo = uo.v;
        uaq = ua_.v;
    };
    auto stagex = [&](int slot) {          // pi-permuted: frags land verbatim
        _Float16* xp = &xb[slot][m * XPAD];
        *(f16x8*)(xp + 8 * g) = bxo;                   // obs -> cols 8g..8g+7
        if (g < 2) *(f16x4*)(xp + 32 + 8 * g) = uaq;   // act -> cols 32+8g..+3
    };

    if (!isA) {
        loadx(); cvtx(); stagex(0);       // x_0 -> slot 0
        loadx(); cvtx(); stagex(1);       // x_1 -> slot 1
        loadx();                          // x_2 in regs (cvt at t=0)
    }
    f32x4 cr = {0.f, 0.f, 0.f, 0.f};
    float* pOut = out + (size_t)((w + 3) & 3) * NSEQ + n0 + lane;

    __syncthreads();

    // A: x-partials for t=0 from xb[0]
    f32x4 pP1[4], pP2[4];
    if (isA) {
        const _Float16* xq = &xb[0][m * XPAD];
        f16x8 f2 = *(const f16x8*)(xq + 8 * g);
        f16x8 f3 = *(const f16x8*)(xq + 32 + 8 * g);
        const f32x4 z = {0.f, 0.f, 0.f, 0.f};
#pragma unroll
        for (int e = 0; e < 4; e++) {
            pP1[e] = __builtin_amdgcn_mfma_f32_16x16x32_f16(AW[e][2], f2, z, 0, 0, 0);
            pP2[e] = __builtin_amdgcn_mfma_f32_16x16x32_f16(AW[e][3], f3, z, 0, 0, 0);
        }
    }
    int xsA = 1;                          // A tail reads slot (t+1)%3
    int xsB = 2;                          // B stages slot (t+2)%3

#pragma unroll 2
    for (int t = 0; t < T_STEPS; ++t) {
        const int cb  = t & 1;
        const int nb2 = cb ^ 1;
        // LDS-only barrier: B's global x loads may span it
        asm volatile("s_waitcnt lgkmcnt(0)\n\ts_barrier" ::: "memory");

        if (isA) {
            // depth-1 h-MFMAs into precomputed x-partials
            const _Float16* bp = &Hbuf[cb][m * HPADH];
            f16x8 f0 = *(const f16x8*)(bp + 8 * g);           // h k 0..31
            f16x8 f1 = *(const f16x8*)(bp + 32 + 8 * g);      // h k 32..63
            f32x4 acc[4];
            __builtin_amdgcn_s_setprio(1);
#pragma unroll
            for (int e = 0; e < 4; e++) {
                f32x4 a1 = __builtin_amdgcn_mfma_f32_16x16x32_f16(AW[e][0], f0, pP1[e], 0, 0, 0);
                f32x4 a2 = __builtin_amdgcn_mfma_f32_16x16x32_f16(AW[e][1], f1, pP2[e], 0, 0, 0);
                acc[e] = a1 + a2;
            }
            __builtin_amdgcn_s_setprio(0);

            // cell update (fused single-rcp, R17 formulas verbatim)
            float h4[4];
#pragma unroll
            for (int r = 0; r < 4; r++) {
                float ef = __builtin_amdgcn_exp2f(acc[2][r] * -LOG2E);
                float ei = __builtin_amdgcn_exp2f(acc[0][r] * -LOG2E);
                float ej = __builtin_amdgcn_exp2f(acc[1][r] * (-2.0f * LOG2E));
                float Fv = 1.0f + ef, Av = 1.0f + ei, Bv = 1.0f + ej;
                float AB = Av * Bv;
                float num = fmaf(cr[r], AB, Fv * (Bv - 2.0f));
                float c = num * __builtin_amdgcn_rcpf(Fv * AB);
                cr[r] = c;
                float ec = __builtin_amdgcn_exp2f(c * (-2.0f * LOG2E));
                float eo = __builtin_amdgcn_exp2f(acc[3][r] * -LOG2E);
                float Dv = 1.0f + ec, Ev = 1.0f + eo;
                h4[r] = (Dv - 2.0f) * __builtin_amdgcn_rcpf(Dv * Ev);
            }
            F4 hi_;
            hi_.h2[0] = pkrtz(h4[0], h4[1]);
            hi_.h2[1] = pkrtz(h4[2], h4[3]);
            *(f16x4*)(&Hbuf[nb2][m * HPADH + sigb]) = hi_.v;

            float p = h4[0] * wdv[0];
            p = fmaf(h4[1], wdv[1], p);
            p = fmaf(h4[2], wdv[2], p);
            p = fmaf(h4[3], wdv[3], p);
            partb[cb][m][4 * w + g] = p;

            // tail: x-partials for t+1 from xb[(t+1)%3] (staged >= 1 barrier ago)
            if (t + 1 < T_STEPS) {
                const _Float16* xq = &xb[xsA][m * XPAD];
                xsA = (xsA == 2) ? 0 : xsA + 1;
                f16x8 f2 = *(const f16x8*)(xq + 8 * g);
                f16x8 f3 = *(const f16x8*)(xq + 32 + 8 * g);
                const f32x4 z = {0.f, 0.f, 0.f, 0.f};
                __builtin_amdgcn_s_setprio(1);
#pragma unroll
                for (int e = 0; e < 4; e++) {
                    pP1[e] = __builtin_amdgcn_mfma_f32_16x16x32_f16(AW[e][2], f2, z, 0, 0, 0);
                    pP2[e] = __builtin_amdgcn_mfma_f32_16x16x32_f16(AW[e][3], f3, z, 0, 0, 0);
                }
                __builtin_amdgcn_s_setprio(0);
            }
        } else {
            // producer: cvt+stage x_{t+2}; issue x_{t+3}; output duty for row t-1
            if (t + 2 < T_STEPS) {
                cvtx();
                stagex(xsB);
                xsB = (xsB == 2) ? 0 : xsB + 1;
            }
            if (t + 3 < T_STEPS) loadx();
            if (t > 0 && w == (t & 3) && lane < 16) {
                const float* pp = &partb[nb2][lane][0];
                f32x4 q0 = *(const f32x4*)pp;
                f32x4 q1 = *(const f32x4*)(pp + 4);
                f32x4 q2 = *(const f32x4*)(pp + 8);
                f32x4 q3 = *(const f32x4*)(pp + 12);
                f32x4 s4 = (q0 + q1) + (q2 + q3);
                *pOut = s4[0] + s4[1] + s4[2] + s4[3] + bd;
                pOut += 4 * NSEQ;
            }
        }
    }

    // final row (t = T_STEPS-1 partials in partb[1]); B-wave 0 serves it
    __syncthreads();
    if (!isA && w == 0 && lane < 16) {
        const float* pp = &partb[1][lane][0];
        f32x4 q0 = *(const f32x4*)pp;
        f32x4 q1 = *(const f32x4*)(pp + 4);
        f32x4 q2 = *(const f32x4*)(pp + 8);
        f32x4 q3 = *(const f32x4*)(pp + 12);
        f32x4 s4 = (q0 + q1) + (q2 + q3);
        *pOut = s4[0] + s4[1] + s4[2] + s4[3] + bd;
    }
}

extern "C" void kernel_launch(void* const* d_in, const int* in_sizes, int n_in,
                              void* d_out, int out_size, void* d_ws, size_t ws_size,
                              hipStream_t stream) {
    (void)in_sizes; (void)n_in; (void)d_ws; (void)ws_size; (void)out_size;
    const float* obss    = (const float*)d_in[0];
    const float* actions = (const float*)d_in[1];
    const float* W       = (const float*)d_in[2];
    const float* b       = (const float*)d_in[3];
    const float* Wdec    = (const float*)d_in[4];
    const float* bdec    = (const float*)d_in[5];
    float* out = (float*)d_out;
    lstm_fused<<<dim3(NSEQ / NB), dim3(512), 0, stream>>>(obss, actions, W, b, Wdec, bdec, out);
}